// Round 6
// baseline (252.016 us; speedup 1.0000x reference)
//
#include <hip/hip_runtime.h>
#include <hip/hip_bf16.h>
#include <cstdint>

typedef _Float16 f16;
typedef _Float16 half8 __attribute__((ext_vector_type(8)));
typedef float f32x4 __attribute__((ext_vector_type(4)));

#define SCALE 0.125f

// async global->LDS, 16B per lane, dest = wave-uniform base + lane*16
#define GLL(src, dst) __builtin_amdgcn_global_load_lds( \
    (const __attribute__((address_space(1))) unsigned int*)(src), \
    (__attribute__((address_space(3))) unsigned int*)(dst), 16, 0, 0)

// ---------------- fused prep: x f32 -> x16 (row-major f16) + xT (64,1024,256) f16 ----------------
__global__ __launch_bounds__(256) void prep_xf(const float* __restrict__ x, f16* __restrict__ x16,
                                               f16* __restrict__ xT) {
  __shared__ f16 tile[32][33];
  int b = blockIdx.z, nt = blockIdx.y, dt = blockIdx.x;
  int c = threadIdx.x & 31, rp = threadIdx.x >> 5;
  const float* xb = x + ((size_t)b*256 + nt*32)*1024 + dt*32;
  f16* x16b = x16 + ((size_t)b*256 + nt*32)*1024 + dt*32;
#pragma unroll
  for (int p = 0; p < 4; ++p) {
    int r = p*8 + rp;
    f16 h = (f16)xb[(size_t)r*1024 + c];
    x16b[(size_t)r*1024 + c] = h;
    tile[r][c] = h;
  }
  __syncthreads();
  f16* o = xT + ((size_t)b*1024 + dt*32)*256 + nt*32;
#pragma unroll
  for (int p = 0; p < 4; ++p) { int r = p*8 + rp; o[(size_t)r*256 + c] = tile[c][r]; }
}

// ---------------- prep: Wkv (1024,1024) f32 -> WkvT f16 ----
__global__ __launch_bounds__(256) void prep_WkvT(const float* __restrict__ W, f16* __restrict__ Wt) {
  __shared__ float tile[32][33];
  int kt = blockIdx.x, nt = blockIdx.y;
  int c = threadIdx.x & 31, rp = threadIdx.x >> 5;
#pragma unroll
  for (int p = 0; p < 4; ++p) { int r = p*8+rp; tile[r][c] = W[(size_t)(kt*32 + r)*1024 + nt*32 + c]; }
  __syncthreads();
#pragma unroll
  for (int p = 0; p < 4; ++p) { int r = p*8+rp; Wt[(size_t)(nt*32 + r)*1024 + kt*32 + c] = (f16)tile[c][r]; }
}

// ---------------- prep: Wspec (256,768) f32 -> WspecT (512,256) f16 ----
__global__ __launch_bounds__(256) void prep_WspecT(const float* __restrict__ W, f16* __restrict__ Wt) {
  __shared__ float tile[32][33];
  int jt = blockIdx.x, ct = blockIdx.y;
  int c = threadIdx.x & 31, rp = threadIdx.x >> 5;
#pragma unroll
  for (int p = 0; p < 4; ++p) { int r = p*8+rp; tile[r][c] = W[(size_t)(ct*32 + r)*768 + jt*32 + c]; }
  __syncthreads();
#pragma unroll
  for (int p = 0; p < 4; ++p) { int r = p*8+rp; Wt[(size_t)(jt*32 + r)*256 + ct*32 + c] = (f16)tile[c][r]; }
}

// ---------------- 128x128x(32*KSTEPS) f16 GEMM, double-buffered + counted vmcnt (T3/T4) ----
template<int KSTEPS, int AST, int BST, int CST, bool SCALEQ>
__global__ __launch_bounds__(256) void gemm128(const f16* __restrict__ Ag, const f16* __restrict__ Bg,
                                               f16* __restrict__ Cg, size_t aB, size_t bB, size_t cB) {
  __shared__ f16 As[2][128*32];
  __shared__ f16 Bs[2][128*32];
  const f16* A = Ag + (size_t)blockIdx.z*aB;
  const f16* B = Bg + (size_t)blockIdx.z*bB;
  f16* C = Cg + (size_t)blockIdx.z*cB;
  int t = threadIdx.x, lane = t & 63, wave = t >> 6;
  int l15 = lane & 15, l4 = lane >> 4;
  int wm = wave & 1, wn = wave >> 1;
  size_t m0 = (size_t)blockIdx.x*128, n0 = (size_t)blockIdx.y*128;
  float cscale = (SCALEQ && n0 < 256) ? SCALE : 1.0f;
  f32x4 acc[4][4];
#pragma unroll
  for (int i=0;i<4;++i)
#pragma unroll
    for (int j=0;j<4;++j) acc[i][j] = (f32x4){0.f,0.f,0.f,0.f};
  int rowS[2], chS[2];
#pragma unroll
  for (int c=0;c<2;++c) {
    int slot = c*256 + t;
    rowS[c] = slot >> 2;
    chS[c]  = (slot & 3) ^ ((slot >> 3) & 3);
  }
  int pc = (l4 ^ ((l15 >> 1) & 3)) * 8;

  auto STAGE = [&](int buf, int ks) {   // 4 GLL per thread -> uniform 4/wave
    int k0 = ks*32;
#pragma unroll
    for (int c=0;c<2;++c) {
      GLL(A + (m0 + rowS[c])*(size_t)AST + k0 + chS[c]*8, &As[buf][(c*256 + wave*64)*8]);
      GLL(B + (n0 + rowS[c])*(size_t)BST + k0 + chS[c]*8, &Bs[buf][(c*256 + wave*64)*8]);
    }
  };

  STAGE(0, 0);
#pragma unroll 2
  for (int ks = 0; ks < KSTEPS; ++ks) {
    int cur = ks & 1;
    if (ks + 1 < KSTEPS) {
      STAGE(cur ^ 1, ks + 1);
      asm volatile("s_waitcnt vmcnt(4)" ::: "memory");   // prior tile landed; next 4 in flight
    } else {
      asm volatile("s_waitcnt vmcnt(0)" ::: "memory");
    }
    __builtin_amdgcn_s_barrier();
    __builtin_amdgcn_sched_barrier(0);
    half8 a[4], bb[4];
    const f16* Af = &As[cur][(wm*64 + l15)*32 + pc];
    const f16* Bf = &Bs[cur][(wn*64 + l15)*32 + pc];
#pragma unroll
    for (int mi=0;mi<4;++mi) a[mi]  = *(const half8*)(Af + mi*16*32);
#pragma unroll
    for (int ni=0;ni<4;++ni) bb[ni] = *(const half8*)(Bf + ni*16*32);
    __builtin_amdgcn_s_setprio(1);
#pragma unroll
    for (int mi=0;mi<4;++mi)
#pragma unroll
      for (int ni=0;ni<4;++ni)
        acc[mi][ni] = __builtin_amdgcn_mfma_f32_16x16x32_f16(a[mi], bb[ni], acc[mi][ni], 0,0,0);
    __builtin_amdgcn_s_setprio(0);
    __builtin_amdgcn_sched_barrier(0);
    __builtin_amdgcn_s_barrier();   // licenses next iteration's STAGE overwrite
  }
#pragma unroll
  for (int mi=0;mi<4;++mi)
#pragma unroll
    for (int ni=0;ni<4;++ni)
#pragma unroll
      for (int j=0;j<4;++j) {
        size_t row = m0 + wm*64 + mi*16 + 4*l4 + j;
        size_t col = n0 + wn*64 + ni*16 + l15;
        C[row*CST + col] = (f16)(acc[mi][ni][j] * cscale);
      }
}

// ---------------- qattn: per (b,h): q = x_center @ Wq, attn over 256, out -> attnout (64,512) f32 ----
__global__ __launch_bounds__(256) void qattn(const float* __restrict__ x, const float* __restrict__ Wq,
                                             const f16* __restrict__ kv, float* __restrict__ attnout) {
  int b = blockIdx.x, h = blockIdx.y;
  int t = threadIdx.x;
  __shared__ float xc[1024];
  __shared__ float qh[64];
  __shared__ float p[256];
  __shared__ float part[4][64];
  __shared__ float redw[4];
  const float* xcg = x + ((size_t)b*256 + 128)*1024;
#pragma unroll
  for (int i = 0; i < 4; ++i) xc[t + 256*i] = xcg[t + 256*i];
  __syncthreads();
  int d = t & 63, chunk = t >> 6;
  {
    float s = 0.f;
    const float* wq = Wq + (size_t)(chunk*256)*512 + h*64 + d;
#pragma unroll 8
    for (int c = 0; c < 256; ++c) s += xc[chunk*256 + c] * wq[(size_t)c*512];
    part[chunk][d] = s;
  }
  __syncthreads();
  if (t < 64) qh[t] = part[0][t]+part[1][t]+part[2][t]+part[3][t];
  __syncthreads();
  {
    const f16* kp = kv + ((size_t)b*256 + t)*1024 + h*64;
    float acc = 0.f;
#pragma unroll
    for (int d8 = 0; d8 < 8; ++d8) {
      half8 kk = *(const half8*)(kp + d8*8);
#pragma unroll
      for (int j = 0; j < 8; ++j) acc += (float)kk[j] * qh[d8*8+j];
    }
    p[t] = acc * SCALE;
  }
  __syncthreads();
  int lane = t & 63, wid = t >> 6;
  float v = p[t];
#pragma unroll
  for (int o = 32; o >= 1; o >>= 1) v = fmaxf(v, __shfl_xor(v, o));
  if (lane == 0) redw[wid] = v;
  __syncthreads();
  float m = fmaxf(fmaxf(redw[0],redw[1]),fmaxf(redw[2],redw[3]));
  float e = __expf(p[t] - m);
  __syncthreads();
  v = e;
#pragma unroll
  for (int o = 32; o >= 1; o >>= 1) v += __shfl_xor(v, o);
  if (lane == 0) redw[wid] = v;
  __syncthreads();
  float Z = redw[0]+redw[1]+redw[2]+redw[3];
  p[t] = e / Z;
  __syncthreads();
  {
    float o = 0.f;
    const f16* vp = kv + ((size_t)b*256 + chunk*64)*1024 + 512 + h*64 + d;
#pragma unroll 8
    for (int n = 0; n < 64; ++n) o += p[chunk*64 + n] * (float)vp[(size_t)n*1024];
    part[chunk][d] = o;
  }
  __syncthreads();
  if (t < 64) attnout[(size_t)b*512 + h*64 + t] = part[0][t]+part[1][t]+part[2][t]+part[3][t];
}

// ---------------- spatial partial ----------------
__global__ __launch_bounds__(256) void spatialp(const float* __restrict__ attnout, const float* __restrict__ Wout,
                                                float* __restrict__ partial) {
  int ic = blockIdx.x, b = blockIdx.y;
  int t = threadIdx.x;
  __shared__ float ao[128];
  if (t < 128) ao[t] = attnout[(size_t)b*512 + ic*128 + t];
  __syncthreads();
  const float* W = Wout + (size_t)ic*128*1024 + t*4;
  f32x4 acc0 = (f32x4){0.f,0.f,0.f,0.f};
  f32x4 acc1 = (f32x4){0.f,0.f,0.f,0.f};
#pragma unroll 4
  for (int i = 0; i < 128; i += 2) {
    f32x4 w0 = *(const f32x4*)(W + (size_t)i*1024);
    f32x4 w1 = *(const f32x4*)(W + (size_t)(i+1)*1024);
    float a0 = ao[i], a1 = ao[i+1];
    acc0[0] += a0*w0[0]; acc0[1] += a0*w0[1]; acc0[2] += a0*w0[2]; acc0[3] += a0*w0[3];
    acc1[0] += a1*w1[0]; acc1[1] += a1*w1[1]; acc1[2] += a1*w1[2]; acc1[3] += a1*w1[3];
  }
  f32x4 acc;
#pragma unroll
  for (int j=0;j<4;++j) acc[j] = acc0[j] + acc1[j];
  *(f32x4*)(partial + ((size_t)(b*4 + ic))*1024 + t*4) = acc;
}

// ---------------- spatial reduce ----------------
__global__ __launch_bounds__(256) void spatialr(const float* __restrict__ partial, const float* __restrict__ bout,
                                                float* __restrict__ spatial) {
  int b = blockIdx.x, t = threadIdx.x;
  f32x4 s = *(const f32x4*)(bout + t*4);
#pragma unroll
  for (int ic = 0; ic < 4; ++ic) {
    f32x4 p = *(const f32x4*)(partial + ((size_t)(b*4 + ic))*1024 + t*4);
#pragma unroll
    for (int j=0;j<4;++j) s[j] += p[j];
  }
  *(f32x4*)(spatial + (size_t)b*1024 + t*4) = s;
}

// ---------------- spec v5: 32i x 1024e per block; 16 phases (8 ksteps x 2 e-halves); ----
// 2 blocks/CU (LDS ~69KB, VGPR<=128 via launch_bounds(512,4)); counted vmcnt(5); no-max softmax.
// SCALE pre-folded into q_s (exact pow2). XCD-pinned batches.
__global__ __launch_bounds__(512, 4) void speck(const f16* __restrict__ qks, const float* __restrict__ spatial,
                                                float* __restrict__ r) {
  __shared__ f16 Bs[2][512*32];                        // 2 x 32 KB: e-half tile per phase
  __shared__ f16 As[2][32*32];                         // 2 x 2 KB
  __shared__ __attribute__((aligned(16))) float sz[32*8];
  int bid = blockIdx.x;
  int xcd = bid & 7, q = bid >> 3;
  int b = xcd*8 + (q >> 5);                            // batch pinned to one XCD
  int iblk = q & 31;
  int t = threadIdx.x, lane = t & 63, wave = t >> 6;
  int l15 = lane & 15, l4 = lane >> 4;
  int ew = wave;
  const f16* qs = qks + (size_t)b*1024*512;
  int i0 = iblk*32;

  f32x4 acc[2][8];                                     // rt x (h*4+ct4): 64 VGPR
#pragma unroll
  for (int rt=0;rt<2;++rt)
#pragma unroll
    for (int ct=0;ct<8;++ct) acc[rt][ct] = (f32x4){0.f,0.f,0.f,0.f};
  int pc = (l4 ^ ((l15 >> 1) & 3)) * 8;

  // uniform 5 GLL per wave per phase: 4 B-half + 1 A (wave pairs duplicate A, benign WAW)
  auto STAGE = [&](int buf, int p) {
    int ks = p >> 1, h = p & 1;
    int k0 = ks*32;
#pragma unroll
    for (int c = 0; c < 4; ++c) {
      int slot = c*512 + t;
      int row = slot >> 2;
      int ch = (slot & 3) ^ ((slot >> 3) & 3);
      GLL(qs + (size_t)(512*h + row)*512 + 256 + k0 + ch*8, &Bs[buf][(c*512 + wave*64)*8]);
    }
    {
      int slot = ((wave & 1) << 6) + lane;
      int row = slot >> 2;
      int ch = (slot & 3) ^ ((slot >> 3) & 3);
      GLL(qs + (size_t)(i0 + row)*512 + k0 + ch*8, &As[buf][(((wave & 1) << 6))*8]);
    }
  };

  STAGE(0, 0);
#pragma unroll
  for (int p = 0; p < 16; ++p) {
    int buf = p & 1, h = p & 1;
    if (p < 15) {
      STAGE(buf ^ 1, p + 1);
      asm volatile("s_waitcnt vmcnt(5)" ::: "memory");  // this phase's 5 landed; next 5 in flight
    } else {
      asm volatile("s_waitcnt vmcnt(0)" ::: "memory");
    }
    __builtin_amdgcn_s_barrier();
    __builtin_amdgcn_sched_barrier(0);
    half8 a0 = *(const half8*)(&As[buf][(l15)*32 + pc]);
    half8 a1 = *(const half8*)(&As[buf][(16 + l15)*32 + pc]);
    __builtin_amdgcn_s_setprio(1);
#pragma unroll
    for (int c4 = 0; c4 < 4; ++c4) {
      half8 bb = *(const half8*)(&Bs[buf][(ew*64 + c4*16 + l15)*32 + pc]);
      acc[0][h*4+c4] = __builtin_amdgcn_mfma_f32_16x16x32_f16(a0, bb, acc[0][h*4+c4], 0,0,0);
      acc[1][h*4+c4] = __builtin_amdgcn_mfma_f32_16x16x32_f16(a1, bb, acc[1][h*4+c4], 0,0,0);
    }
    __builtin_amdgcn_s_setprio(0);
    __builtin_amdgcn_sched_barrier(0);
    __builtin_amdgcn_s_barrier();
  }
  // ---- no-max softmax: exp directly (f32-safe: L <= ~46 worst-case), row sums across 8 waves ----
  float zr[2][4];
#pragma unroll
  for (int rt=0;rt<2;++rt)
#pragma unroll
    for (int jj=0;jj<4;++jj) {
      float zz = 0.f;
#pragma unroll
      for (int ct=0;ct<8;++ct) {
        float e = __expf(acc[rt][ct][jj]);
        acc[rt][ct][jj] = e;
        zz += e;
      }
#pragma unroll
      for (int o=1;o<16;o<<=1) zz += __shfl_xor(zz, o);
      zr[rt][jj] = zz;
    }
  if (l15 == 0) {
#pragma unroll
    for (int rt=0;rt<2;++rt)
#pragma unroll
      for (int jj=0;jj<4;++jj) sz[(rt*16 + 4*l4 + jj)*8 + wave] = zr[rt][jj];
  }
  __syncthreads();
  float f[2][4];
#pragma unroll
  for (int rt=0;rt<2;++rt)
#pragma unroll
    for (int jj=0;jj<4;++jj) {
      int row = rt*16 + 4*l4 + jj;
      f32x4 lo = *(const f32x4*)(&sz[row*8]);
      f32x4 hi = *(const f32x4*)(&sz[row*8+4]);
      float zz = (lo[0]+lo[1]+lo[2]+lo[3]) + (hi[0]+hi[1]+hi[2]+hi[3]);
      f[rt][jj] = spatial[(size_t)b*1024 + i0 + row] / zz;
    }
  float* rb = r + (size_t)b*1024;
#pragma unroll
  for (int ct=0;ct<8;++ct) {
    float v = 0.f;
#pragma unroll
    for (int rt=0;rt<2;++rt)
#pragma unroll
      for (int jj=0;jj<4;++jj) v += f[rt][jj]*acc[rt][ct][jj];
    v += __shfl_xor(v, 16);
    v += __shfl_xor(v, 32);
    if (l4 == 0) {
      int e = (ct < 4) ? (ew*64 + ct*16 + l15) : (512 + ew*64 + (ct-4)*16 + l15);
      atomicAdd(rb + e, v);
    }
  }
}

// ---------------- broadcast: out[b,n,:] = r[b,:] ----------------
__global__ __launch_bounds__(256) void bcast(const float* __restrict__ r, float* __restrict__ out) {
  size_t row = blockIdx.x;
  int b = (int)(row >> 8);
  f32x4 v = *(const f32x4*)(r + (size_t)b*1024 + threadIdx.x*4);
  *(f32x4*)(out + row*1024 + (size_t)threadIdx.x*4) = v;
}

extern "C" void kernel_launch(void* const* d_in, const int* in_sizes, int n_in,
                              void* d_out, int out_size, void* d_ws, size_t ws_size,
                              hipStream_t stream) {
  const float* x     = (const float*)d_in[0];
  const float* Wq    = (const float*)d_in[1];
  const float* Wkv   = (const float*)d_in[2];
  const float* Wout  = (const float*)d_in[3];
  const float* bout  = (const float*)d_in[4];
  const float* Wspec = (const float*)d_in[5];
  float* out = (float*)d_out;
  char* ws = (char*)d_ws;
  // workspace aliases (stream-ordered):
  //   qks @0 64MB (gemm_qs -> speck); kv @0 32MB alias (dead before gemm_qs);
  //   partial @0 1MB alias (between qattn and gemm_qs); x16 @32M alias (dead after gemm_kv)
  f16*  qks     = (f16*)(ws);
  f16*  kv      = (f16*)(ws);
  float* partial = (float*)(ws);
  f16*  x16     = (f16*)(ws + 33554432);
  f16*  xT      = (f16*)(ws + 67108864);         // 32 MB
  f16*  WkvT    = (f16*)(ws + 100663296);        // 2 MB
  f16*  WspecT  = (f16*)(ws + 102760448);        // 256 KB
  float* attnout = (float*)(ws + 103022592);     // 128 KB
  float* spatial = (float*)(ws + 103153664);     // 256 KB
  float* rvec    = (float*)(ws + 103415808);     // 256 KB
  (void)in_sizes; (void)n_in; (void)out_size; (void)ws_size;

  prep_xf    <<<dim3(32, 8, 64), dim3(256), 0, stream>>>(x, x16, xT);
  prep_WkvT  <<<dim3(32, 32),    dim3(256), 0, stream>>>(Wkv, WkvT);
  prep_WspecT<<<dim3(16, 8),     dim3(256), 0, stream>>>(Wspec, WspecT);
  gemm128<32,1024,1024,1024,false><<<dim3(128, 8, 1), dim3(256), 0, stream>>>(x16, WkvT, kv, 0, 0, 0);
  qattn      <<<dim3(64, 8),     dim3(256), 0, stream>>>(x, Wq, kv, attnout);
  spatialp   <<<dim3(4, 64),     dim3(256), 0, stream>>>(attnout, Wout, partial);
  spatialr   <<<dim3(64),        dim3(256), 0, stream>>>(partial, bout, spatial);
  gemm128<8,256,256,512,true><<<dim3(8, 4, 64), dim3(256), 0, stream>>>(xT, WspecT, qks,
                                                                   (size_t)1024*256, 0, (size_t)1024*512);
  hipMemsetAsync(rvec, 0, 64*1024*sizeof(float), stream);
  speck      <<<dim3(2048),      dim3(512), 0, stream>>>(qks, spatial, rvec);
  bcast      <<<dim3(16384),     dim3(256), 0, stream>>>(rvec, out);
}

// Round 7
// 239.425 us; speedup vs baseline: 1.0526x; 1.0526x over previous
//
#include <hip/hip_runtime.h>
#include <hip/hip_bf16.h>
#include <cstdint>

typedef _Float16 f16;
typedef _Float16 half8 __attribute__((ext_vector_type(8)));
typedef float f32x4 __attribute__((ext_vector_type(4)));

#define SCALE 0.125f

// async global->LDS, 16B per lane, dest = wave-uniform base + lane*16
#define GLL(src, dst) __builtin_amdgcn_global_load_lds( \
    (const __attribute__((address_space(1))) unsigned int*)(src), \
    (__attribute__((address_space(3))) unsigned int*)(dst), 16, 0, 0)

// ---------------- fused prep: x f32 -> x16 (row-major f16) + xT (64,1024,256) f16 ----------------
__global__ __launch_bounds__(256) void prep_xf(const float* __restrict__ x, f16* __restrict__ x16,
                                               f16* __restrict__ xT) {
  __shared__ f16 tile[32][33];
  int b = blockIdx.z, nt = blockIdx.y, dt = blockIdx.x;
  int c = threadIdx.x & 31, rp = threadIdx.x >> 5;
  const float* xb = x + ((size_t)b*256 + nt*32)*1024 + dt*32;
  f16* x16b = x16 + ((size_t)b*256 + nt*32)*1024 + dt*32;
#pragma unroll
  for (int p = 0; p < 4; ++p) {
    int r = p*8 + rp;
    f16 h = (f16)xb[(size_t)r*1024 + c];
    x16b[(size_t)r*1024 + c] = h;
    tile[r][c] = h;
  }
  __syncthreads();
  f16* o = xT + ((size_t)b*1024 + dt*32)*256 + nt*32;
#pragma unroll
  for (int p = 0; p < 4; ++p) { int r = p*8 + rp; o[(size_t)r*256 + c] = tile[c][r]; }
}

// ---------------- prep: Wkv (1024,1024) f32 -> WkvT f16 ----
__global__ __launch_bounds__(256) void prep_WkvT(const float* __restrict__ W, f16* __restrict__ Wt) {
  __shared__ float tile[32][33];
  int kt = blockIdx.x, nt = blockIdx.y;
  int c = threadIdx.x & 31, rp = threadIdx.x >> 5;
#pragma unroll
  for (int p = 0; p < 4; ++p) { int r = p*8+rp; tile[r][c] = W[(size_t)(kt*32 + r)*1024 + nt*32 + c]; }
  __syncthreads();
#pragma unroll
  for (int p = 0; p < 4; ++p) { int r = p*8+rp; Wt[(size_t)(nt*32 + r)*1024 + kt*32 + c] = (f16)tile[c][r]; }
}

// ---------------- prep: Wspec (256,768) f32 -> WspecT (512,256) f16 ----
__global__ __launch_bounds__(256) void prep_WspecT(const float* __restrict__ W, f16* __restrict__ Wt) {
  __shared__ float tile[32][33];
  int jt = blockIdx.x, ct = blockIdx.y;
  int c = threadIdx.x & 31, rp = threadIdx.x >> 5;
#pragma unroll
  for (int p = 0; p < 4; ++p) { int r = p*8+rp; tile[r][c] = W[(size_t)(ct*32 + r)*768 + jt*32 + c]; }
  __syncthreads();
#pragma unroll
  for (int p = 0; p < 4; ++p) { int r = p*8+rp; Wt[(size_t)(jt*32 + r)*256 + ct*32 + c] = (f16)tile[c][r]; }
}

// ---------------- 128x128x(32*KSTEPS) f16 GEMM, double-buffered + counted vmcnt (T3/T4) ----
template<int KSTEPS, int AST, int BST, int CST, bool SCALEQ>
__global__ __launch_bounds__(256) void gemm128(const f16* __restrict__ Ag, const f16* __restrict__ Bg,
                                               f16* __restrict__ Cg, size_t aB, size_t bB, size_t cB) {
  __shared__ f16 As[2][128*32];
  __shared__ f16 Bs[2][128*32];
  const f16* A = Ag + (size_t)blockIdx.z*aB;
  const f16* B = Bg + (size_t)blockIdx.z*bB;
  f16* C = Cg + (size_t)blockIdx.z*cB;
  int t = threadIdx.x, lane = t & 63, wave = t >> 6;
  int l15 = lane & 15, l4 = lane >> 4;
  int wm = wave & 1, wn = wave >> 1;
  size_t m0 = (size_t)blockIdx.x*128, n0 = (size_t)blockIdx.y*128;
  float cscale = (SCALEQ && n0 < 256) ? SCALE : 1.0f;
  f32x4 acc[4][4];
#pragma unroll
  for (int i=0;i<4;++i)
#pragma unroll
    for (int j=0;j<4;++j) acc[i][j] = (f32x4){0.f,0.f,0.f,0.f};
  int rowS[2], chS[2];
#pragma unroll
  for (int c=0;c<2;++c) {
    int slot = c*256 + t;
    rowS[c] = slot >> 2;
    chS[c]  = (slot & 3) ^ ((slot >> 3) & 3);
  }
  int pc = (l4 ^ ((l15 >> 1) & 3)) * 8;

  auto STAGE = [&](int buf, int ks) {   // 4 GLL per thread -> uniform 4/wave
    int k0 = ks*32;
#pragma unroll
    for (int c=0;c<2;++c) {
      GLL(A + (m0 + rowS[c])*(size_t)AST + k0 + chS[c]*8, &As[buf][(c*256 + wave*64)*8]);
      GLL(B + (n0 + rowS[c])*(size_t)BST + k0 + chS[c]*8, &Bs[buf][(c*256 + wave*64)*8]);
    }
  };

  STAGE(0, 0);
#pragma unroll 2
  for (int ks = 0; ks < KSTEPS; ++ks) {
    int cur = ks & 1;
    if (ks + 1 < KSTEPS) {
      STAGE(cur ^ 1, ks + 1);
      asm volatile("s_waitcnt vmcnt(4)" ::: "memory");   // prior tile landed; next 4 in flight
    } else {
      asm volatile("s_waitcnt vmcnt(0)" ::: "memory");
    }
    __builtin_amdgcn_s_barrier();
    __builtin_amdgcn_sched_barrier(0);
    half8 a[4], bb[4];
    const f16* Af = &As[cur][(wm*64 + l15)*32 + pc];
    const f16* Bf = &Bs[cur][(wn*64 + l15)*32 + pc];
#pragma unroll
    for (int mi=0;mi<4;++mi) a[mi]  = *(const half8*)(Af + mi*16*32);
#pragma unroll
    for (int ni=0;ni<4;++ni) bb[ni] = *(const half8*)(Bf + ni*16*32);
    __builtin_amdgcn_s_setprio(1);
#pragma unroll
    for (int mi=0;mi<4;++mi)
#pragma unroll
      for (int ni=0;ni<4;++ni)
        acc[mi][ni] = __builtin_amdgcn_mfma_f32_16x16x32_f16(a[mi], bb[ni], acc[mi][ni], 0,0,0);
    __builtin_amdgcn_s_setprio(0);
    __builtin_amdgcn_sched_barrier(0);
    __builtin_amdgcn_s_barrier();   // licenses next iteration's STAGE overwrite
  }
#pragma unroll
  for (int mi=0;mi<4;++mi)
#pragma unroll
    for (int ni=0;ni<4;++ni)
#pragma unroll
      for (int j=0;j<4;++j) {
        size_t row = m0 + wm*64 + mi*16 + 4*l4 + j;
        size_t col = n0 + wn*64 + ni*16 + l15;
        C[row*CST + col] = (f16)(acc[mi][ni][j] * cscale);
      }
}

// ---------------- qattn: per (b,h): q = x_center @ Wq, attn over 256, out -> attnout (64,512) f32 ----
__global__ __launch_bounds__(256) void qattn(const float* __restrict__ x, const float* __restrict__ Wq,
                                             const f16* __restrict__ kv, float* __restrict__ attnout) {
  int b = blockIdx.x, h = blockIdx.y;
  int t = threadIdx.x;
  __shared__ float xc[1024];
  __shared__ float qh[64];
  __shared__ float p[256];
  __shared__ float part[4][64];
  __shared__ float redw[4];
  const float* xcg = x + ((size_t)b*256 + 128)*1024;
#pragma unroll
  for (int i = 0; i < 4; ++i) xc[t + 256*i] = xcg[t + 256*i];
  __syncthreads();
  int d = t & 63, chunk = t >> 6;
  {
    float s = 0.f;
    const float* wq = Wq + (size_t)(chunk*256)*512 + h*64 + d;
#pragma unroll 8
    for (int c = 0; c < 256; ++c) s += xc[chunk*256 + c] * wq[(size_t)c*512];
    part[chunk][d] = s;
  }
  __syncthreads();
  if (t < 64) qh[t] = part[0][t]+part[1][t]+part[2][t]+part[3][t];
  __syncthreads();
  {
    const f16* kp = kv + ((size_t)b*256 + t)*1024 + h*64;
    float acc = 0.f;
#pragma unroll
    for (int d8 = 0; d8 < 8; ++d8) {
      half8 kk = *(const half8*)(kp + d8*8);
#pragma unroll
      for (int j = 0; j < 8; ++j) acc += (float)kk[j] * qh[d8*8+j];
    }
    p[t] = acc * SCALE;
  }
  __syncthreads();
  int lane = t & 63, wid = t >> 6;
  float v = p[t];
#pragma unroll
  for (int o = 32; o >= 1; o >>= 1) v = fmaxf(v, __shfl_xor(v, o));
  if (lane == 0) redw[wid] = v;
  __syncthreads();
  float m = fmaxf(fmaxf(redw[0],redw[1]),fmaxf(redw[2],redw[3]));
  float e = __expf(p[t] - m);
  __syncthreads();
  v = e;
#pragma unroll
  for (int o = 32; o >= 1; o >>= 1) v += __shfl_xor(v, o);
  if (lane == 0) redw[wid] = v;
  __syncthreads();
  float Z = redw[0]+redw[1]+redw[2]+redw[3];
  p[t] = e / Z;
  __syncthreads();
  {
    float o = 0.f;
    const f16* vp = kv + ((size_t)b*256 + chunk*64)*1024 + 512 + h*64 + d;
#pragma unroll 8
    for (int n = 0; n < 64; ++n) o += p[chunk*64 + n] * (float)vp[(size_t)n*1024];
    part[chunk][d] = o;
  }
  __syncthreads();
  if (t < 64) attnout[(size_t)b*512 + h*64 + t] = part[0][t]+part[1][t]+part[2][t]+part[3][t];
}

// ---------------- spatial partial ----------------
__global__ __launch_bounds__(256) void spatialp(const float* __restrict__ attnout, const float* __restrict__ Wout,
                                                float* __restrict__ partial) {
  int ic = blockIdx.x, b = blockIdx.y;
  int t = threadIdx.x;
  __shared__ float ao[128];
  if (t < 128) ao[t] = attnout[(size_t)b*512 + ic*128 + t];
  __syncthreads();
  const float* W = Wout + (size_t)ic*128*1024 + t*4;
  f32x4 acc0 = (f32x4){0.f,0.f,0.f,0.f};
  f32x4 acc1 = (f32x4){0.f,0.f,0.f,0.f};
#pragma unroll 4
  for (int i = 0; i < 128; i += 2) {
    f32x4 w0 = *(const f32x4*)(W + (size_t)i*1024);
    f32x4 w1 = *(const f32x4*)(W + (size_t)(i+1)*1024);
    float a0 = ao[i], a1 = ao[i+1];
    acc0[0] += a0*w0[0]; acc0[1] += a0*w0[1]; acc0[2] += a0*w0[2]; acc0[3] += a0*w0[3];
    acc1[0] += a1*w1[0]; acc1[1] += a1*w1[1]; acc1[2] += a1*w1[2]; acc1[3] += a1*w1[3];
  }
  f32x4 acc;
#pragma unroll
  for (int j=0;j<4;++j) acc[j] = acc0[j] + acc1[j];
  *(f32x4*)(partial + ((size_t)(b*4 + ic))*1024 + t*4) = acc;
}

// ---------------- spatial reduce ----------------
__global__ __launch_bounds__(256) void spatialr(const float* __restrict__ partial, const float* __restrict__ bout,
                                                float* __restrict__ spatial) {
  int b = blockIdx.x, t = threadIdx.x;
  f32x4 s = *(const f32x4*)(bout + t*4);
#pragma unroll
  for (int ic = 0; ic < 4; ++ic) {
    f32x4 p = *(const f32x4*)(partial + ((size_t)(b*4 + ic))*1024 + t*4);
#pragma unroll
    for (int j=0;j<4;++j) s[j] += p[j];
  }
  *(f32x4*)(spatial + (size_t)b*1024 + t*4) = s;
}

// ---------------- spec v6: 1024 thr / 16 waves; block = 64i x 1024e; wave owns 64 e-cols ----
// acc = 4x4 f32x4 = 64 regs -> ~120 total -> 16 waves/CU (50% occ). 8 phases, dbuf,
// counted vmcnt (role-dependent: A-staging waves 5, B-only 4). no-max softmax.
// SCALE pre-folded into q_s. XCD-pinned batches (keeps k_s in one XCD's L2).
__global__ __launch_bounds__(1024, 4) void speck(const f16* __restrict__ qks, const float* __restrict__ spatial,
                                                 float* __restrict__ r) {
  __shared__ f16 Bs[2][1024*32];                       // 128 KB
  __shared__ f16 As[2][64*32];                         // 8 KB
  __shared__ __attribute__((aligned(16))) float sz[64*16];  // 4 KB
  __shared__ float zfin[64];
  __shared__ float spat[64];
  int bid = blockIdx.x;
  int xcd = bid & 7, q = bid >> 3;
  int b = xcd*8 + (q >> 4);                            // batch pinned to one XCD
  int iblk = q & 15;
  int t = threadIdx.x, lane = t & 63, wave = t >> 6;
  int l15 = lane & 15, l4 = lane >> 4;
  const f16* qs = qks + (size_t)b*1024*512;
  int i0 = iblk*64;
  if (t < 64) spat[t] = spatial[(size_t)b*1024 + i0 + t];

  f32x4 acc[4][4];
#pragma unroll
  for (int mi=0;mi<4;++mi)
#pragma unroll
    for (int ni=0;ni<4;++ni) acc[mi][ni] = (f32x4){0.f,0.f,0.f,0.f};
  int pc = (l4 ^ ((l15 >> 1) & 3)) * 8;

  // B: 1024 rows x 32 k = 64KB -> 4 GLL/thread. A: 64 rows -> waves 0..3 add 1 GLL.
  auto STAGE = [&](int buf, int ks) {
    int k0 = ks*32;
#pragma unroll
    for (int c = 0; c < 4; ++c) {
      int slot = c*1024 + t;
      int row = slot >> 2;
      int ch = (slot & 3) ^ ((slot >> 3) & 3);
      GLL(qs + (size_t)row*512 + 256 + k0 + ch*8, &Bs[buf][(c*1024 + wave*64)*8]);
    }
    if (wave < 4) {
      int slot = wave*64 + lane;
      int row = slot >> 2;
      int ch = (slot & 3) ^ ((slot >> 3) & 3);
      GLL(qs + (size_t)(i0 + row)*512 + k0 + ch*8, &As[buf][(wave*64)*8]);
    }
  };

  STAGE(0, 0);
#pragma unroll
  for (int p = 0; p < 8; ++p) {
    int buf = p & 1;
    if (p < 7) {
      STAGE(buf ^ 1, p + 1);
      if (wave < 4) asm volatile("s_waitcnt vmcnt(5)" ::: "memory");
      else          asm volatile("s_waitcnt vmcnt(4)" ::: "memory");
    } else {
      asm volatile("s_waitcnt vmcnt(0)" ::: "memory");
    }
    __builtin_amdgcn_s_barrier();
    __builtin_amdgcn_sched_barrier(0);
    half8 a[4];
#pragma unroll
    for (int mi = 0; mi < 4; ++mi) a[mi] = *(const half8*)(&As[buf][(mi*16 + l15)*32 + pc]);
    __builtin_amdgcn_s_setprio(1);
#pragma unroll
    for (int ni = 0; ni < 4; ++ni) {
      half8 bb = *(const half8*)(&Bs[buf][(wave*64 + ni*16 + l15)*32 + pc]);
#pragma unroll
      for (int mi = 0; mi < 4; ++mi)
        acc[mi][ni] = __builtin_amdgcn_mfma_f32_16x16x32_f16(a[mi], bb, acc[mi][ni], 0,0,0);
    }
    __builtin_amdgcn_s_setprio(0);
    __builtin_amdgcn_sched_barrier(0);
    __builtin_amdgcn_s_barrier();
  }
  // ---- no-max softmax (f32-safe): exp in place; row partials over this wave's 64 cols ----
#pragma unroll
  for (int mi=0;mi<4;++mi)
#pragma unroll
    for (int jj=0;jj<4;++jj) {
      float s = 0.f;
#pragma unroll
      for (int ni=0;ni<4;++ni) {
        float e = __expf(acc[mi][ni][jj]);
        acc[mi][ni][jj] = e;
        s += e;
      }
#pragma unroll
      for (int o=1;o<16;o<<=1) s += __shfl_xor(s, o);
      if (l15 == 0) sz[(mi*16 + 4*l4 + jj)*16 + wave] = s;
    }
  __syncthreads();
  // ---- combine Z across 16 waves: 1024 threads, one per (row, wave) cell ----
  {
    float v = sz[t];
#pragma unroll
    for (int o=1;o<16;o<<=1) v += __shfl_xor(v, o);
    if ((t & 15) == 0) zfin[t >> 4] = v;
  }
  __syncthreads();
  // ---- g = spatial / Z; weighted column reduce; atomicAdd r ----
  float f[4][4];
#pragma unroll
  for (int mi=0;mi<4;++mi)
#pragma unroll
    for (int jj=0;jj<4;++jj) {
      int row = mi*16 + 4*l4 + jj;
      f[mi][jj] = spat[row] / zfin[row];
    }
  float* rb = r + (size_t)b*1024;
#pragma unroll
  for (int ni=0;ni<4;++ni) {
    float v = 0.f;
#pragma unroll
    for (int mi=0;mi<4;++mi)
#pragma unroll
      for (int jj=0;jj<4;++jj) v += f[mi][jj]*acc[mi][ni][jj];
    v += __shfl_xor(v, 16);
    v += __shfl_xor(v, 32);
    if (l4 == 0) atomicAdd(rb + wave*64 + ni*16 + l15, v);
  }
}

// ---------------- broadcast: out[b,n,:] = r[b,:] ----------------
__global__ __launch_bounds__(256) void bcast(const float* __restrict__ r, float* __restrict__ out) {
  size_t row = blockIdx.x;
  int b = (int)(row >> 8);
  f32x4 v = *(const f32x4*)(r + (size_t)b*1024 + threadIdx.x*4);
  *(f32x4*)(out + row*1024 + (size_t)threadIdx.x*4) = v;
}

extern "C" void kernel_launch(void* const* d_in, const int* in_sizes, int n_in,
                              void* d_out, int out_size, void* d_ws, size_t ws_size,
                              hipStream_t stream) {
  const float* x     = (const float*)d_in[0];
  const float* Wq    = (const float*)d_in[1];
  const float* Wkv   = (const float*)d_in[2];
  const float* Wout  = (const float*)d_in[3];
  const float* bout  = (const float*)d_in[4];
  const float* Wspec = (const float*)d_in[5];
  float* out = (float*)d_out;
  char* ws = (char*)d_ws;
  // workspace aliases (stream-ordered):
  //   qks @0 64MB (gemm_qs -> speck); kv @0 32MB alias (dead before gemm_qs);
  //   partial @0 1MB alias (between qattn and gemm_qs); x16 @32M alias (dead after gemm_kv)
  f16*  qks     = (f16*)(ws);
  f16*  kv      = (f16*)(ws);
  float* partial = (float*)(ws);
  f16*  x16     = (f16*)(ws + 33554432);
  f16*  xT      = (f16*)(ws + 67108864);         // 32 MB
  f16*  WkvT    = (f16*)(ws + 100663296);        // 2 MB
  f16*  WspecT  = (f16*)(ws + 102760448);        // 256 KB
  float* attnout = (float*)(ws + 103022592);     // 128 KB
  float* spatial = (float*)(ws + 103153664);     // 256 KB
  float* rvec    = (float*)(ws + 103415808);     // 256 KB
  (void)in_sizes; (void)n_in; (void)out_size; (void)ws_size;

  prep_xf    <<<dim3(32, 8, 64), dim3(256), 0, stream>>>(x, x16, xT);
  prep_WkvT  <<<dim3(32, 32),    dim3(256), 0, stream>>>(Wkv, WkvT);
  prep_WspecT<<<dim3(16, 8),     dim3(256), 0, stream>>>(Wspec, WspecT);
  gemm128<32,1024,1024,1024,false><<<dim3(128, 8, 1), dim3(256), 0, stream>>>(x16, WkvT, kv, 0, 0, 0);
  qattn      <<<dim3(64, 8),     dim3(256), 0, stream>>>(x, Wq, kv, attnout);
  spatialp   <<<dim3(4, 64),     dim3(256), 0, stream>>>(attnout, Wout, partial);
  spatialr   <<<dim3(64),        dim3(256), 0, stream>>>(partial, bout, spatial);
  gemm128<8,256,256,512,true><<<dim3(8, 4, 64), dim3(256), 0, stream>>>(xT, WspecT, qks,
                                                                   (size_t)1024*256, 0, (size_t)1024*512);
  hipMemsetAsync(rvec, 0, 64*1024*sizeof(float), stream);
  speck      <<<dim3(1024),      dim3(1024), 0, stream>>>(qks, spatial, rvec);
  bcast      <<<dim3(16384),     dim3(256), 0, stream>>>(rvec, out);
}

// Round 8
// 218.699 us; speedup vs baseline: 1.1523x; 1.0948x over previous
//
#include <hip/hip_runtime.h>
#include <hip/hip_bf16.h>
#include <cstdint>

typedef _Float16 f16;
typedef _Float16 half8 __attribute__((ext_vector_type(8)));
typedef float f32x4 __attribute__((ext_vector_type(4)));

#define SCALE 0.125f

// async global->LDS, 16B per lane, dest = wave-uniform base + lane*16
#define GLL(src, dst) __builtin_amdgcn_global_load_lds( \
    (const __attribute__((address_space(1))) unsigned int*)(src), \
    (__attribute__((address_space(3))) unsigned int*)(dst), 16, 0, 0)

// ---------------- fused prep: x f32 -> x16 (row-major f16) + xT (64,1024,256) f16 ----------------
__global__ __launch_bounds__(256) void prep_xf(const float* __restrict__ x, f16* __restrict__ x16,
                                               f16* __restrict__ xT) {
  __shared__ f16 tile[32][33];
  int b = blockIdx.z, nt = blockIdx.y, dt = blockIdx.x;
  int c = threadIdx.x & 31, rp = threadIdx.x >> 5;
  const float* xb = x + ((size_t)b*256 + nt*32)*1024 + dt*32;
  f16* x16b = x16 + ((size_t)b*256 + nt*32)*1024 + dt*32;
#pragma unroll
  for (int p = 0; p < 4; ++p) {
    int r = p*8 + rp;
    f16 h = (f16)xb[(size_t)r*1024 + c];
    x16b[(size_t)r*1024 + c] = h;
    tile[r][c] = h;
  }
  __syncthreads();
  f16* o = xT + ((size_t)b*1024 + dt*32)*256 + nt*32;
#pragma unroll
  for (int p = 0; p < 4; ++p) { int r = p*8 + rp; o[(size_t)r*256 + c] = tile[c][r]; }
}

// ---------------- prep: Wspec (256,768) f32 -> WspecT (512,256) f16 ----
__global__ __launch_bounds__(256) void prep_WspecT(const float* __restrict__ W, f16* __restrict__ Wt) {
  __shared__ float tile[32][33];
  int jt = blockIdx.x, ct = blockIdx.y;
  int c = threadIdx.x & 31, rp = threadIdx.x >> 5;
#pragma unroll
  for (int p = 0; p < 4; ++p) { int r = p*8+rp; tile[r][c] = W[(size_t)(ct*32 + r)*768 + jt*32 + c]; }
  __syncthreads();
#pragma unroll
  for (int p = 0; p < 4; ++p) { int r = p*8+rp; Wt[(size_t)(jt*32 + r)*256 + ct*32 + c] = (f16)tile[c][r]; }
}

// ---------------- 128x128x(32*KSTEPS) f16 GEMM, double-buffered + counted vmcnt ----
template<int KSTEPS, int AST, int BST, int CST, bool SCALEQ>
__global__ __launch_bounds__(256) void gemm128(const f16* __restrict__ Ag, const f16* __restrict__ Bg,
                                               f16* __restrict__ Cg, size_t aB, size_t bB, size_t cB) {
  __shared__ f16 As[2][128*32];
  __shared__ f16 Bs[2][128*32];
  const f16* A = Ag + (size_t)blockIdx.z*aB;
  const f16* B = Bg + (size_t)blockIdx.z*bB;
  f16* C = Cg + (size_t)blockIdx.z*cB;
  int t = threadIdx.x, lane = t & 63, wave = t >> 6;
  int l15 = lane & 15, l4 = lane >> 4;
  int wm = wave & 1, wn = wave >> 1;
  size_t m0 = (size_t)blockIdx.x*128, n0 = (size_t)blockIdx.y*128;
  float cscale = (SCALEQ && n0 < 256) ? SCALE : 1.0f;
  f32x4 acc[4][4];
#pragma unroll
  for (int i=0;i<4;++i)
#pragma unroll
    for (int j=0;j<4;++j) acc[i][j] = (f32x4){0.f,0.f,0.f,0.f};
  int rowS[2], chS[2];
#pragma unroll
  for (int c=0;c<2;++c) {
    int slot = c*256 + t;
    rowS[c] = slot >> 2;
    chS[c]  = (slot & 3) ^ ((slot >> 3) & 3);
  }
  int pc = (l4 ^ ((l15 >> 1) & 3)) * 8;

  auto STAGE = [&](int buf, int ks) {
    int k0 = ks*32;
#pragma unroll
    for (int c=0;c<2;++c) {
      GLL(A + (m0 + rowS[c])*(size_t)AST + k0 + chS[c]*8, &As[buf][(c*256 + wave*64)*8]);
      GLL(B + (n0 + rowS[c])*(size_t)BST + k0 + chS[c]*8, &Bs[buf][(c*256 + wave*64)*8]);
    }
  };

  STAGE(0, 0);
#pragma unroll 2
  for (int ks = 0; ks < KSTEPS; ++ks) {
    int cur = ks & 1;
    if (ks + 1 < KSTEPS) {
      STAGE(cur ^ 1, ks + 1);
      asm volatile("s_waitcnt vmcnt(4)" ::: "memory");
    } else {
      asm volatile("s_waitcnt vmcnt(0)" ::: "memory");
    }
    __builtin_amdgcn_s_barrier();
    __builtin_amdgcn_sched_barrier(0);
    half8 a[4], bb[4];
    const f16* Af = &As[cur][(wm*64 + l15)*32 + pc];
    const f16* Bf = &Bs[cur][(wn*64 + l15)*32 + pc];
#pragma unroll
    for (int mi=0;mi<4;++mi) a[mi]  = *(const half8*)(Af + mi*16*32);
#pragma unroll
    for (int ni=0;ni<4;++ni) bb[ni] = *(const half8*)(Bf + ni*16*32);
    __builtin_amdgcn_s_setprio(1);
#pragma unroll
    for (int mi=0;mi<4;++mi)
#pragma unroll
      for (int ni=0;ni<4;++ni)
        acc[mi][ni] = __builtin_amdgcn_mfma_f32_16x16x32_f16(a[mi], bb[ni], acc[mi][ni], 0,0,0);
    __builtin_amdgcn_s_setprio(0);
    __builtin_amdgcn_sched_barrier(0);
    __builtin_amdgcn_s_barrier();
  }
#pragma unroll
  for (int mi=0;mi<4;++mi)
#pragma unroll
    for (int ni=0;ni<4;++ni)
#pragma unroll
      for (int j=0;j<4;++j) {
        size_t row = m0 + wm*64 + mi*16 + 4*l4 + j;
        size_t col = n0 + wn*64 + ni*16 + l15;
        C[row*CST + col] = (f16)(acc[mi][ni][j] * cscale);
      }
}

// ---------------- qk: q[b][h*64+d] = x_center @ Wq slice (f32) ----------------
__global__ __launch_bounds__(256) void qk(const float* __restrict__ x, const float* __restrict__ Wq,
                                          float* __restrict__ qbuf) {
  int b = blockIdx.x, h = blockIdx.y;
  int t = threadIdx.x;
  __shared__ float xc[1024];
  __shared__ float part[4][64];
  const float* xcg = x + ((size_t)b*256 + 128)*1024;
#pragma unroll
  for (int i = 0; i < 4; ++i) xc[t + 256*i] = xcg[t + 256*i];
  __syncthreads();
  int d = t & 63, chunk = t >> 6;
  float s = 0.f;
  const float* wq = Wq + (size_t)(chunk*256)*512 + h*64 + d;
#pragma unroll 8
  for (int c = 0; c < 256; ++c) s += xc[chunk*256 + c] * wq[(size_t)c*512];
  part[chunk][d] = s;
  __syncthreads();
  if (t < 64) qbuf[(size_t)b*512 + h*64 + t] = part[0][t]+part[1][t]+part[2][t]+part[3][t];
}

// ---------------- uk: u16[b][h][d] = sum_j Wkv[d][h*64+j] * q[b][h][j] ----------------
// grid (8 h, 32 dc): block covers d-range [dc*32, +32), all 64 b.
__global__ __launch_bounds__(256) void uk(const float* __restrict__ Wkv, const float* __restrict__ qbuf,
                                          f16* __restrict__ u16) {
  int h = blockIdx.x, dc = blockIdx.y;
  int t = threadIdx.x;
  __shared__ float Wk[32][64];
  __shared__ float qT[64][65];
  {
    int j = t & 63, g = t >> 6;
#pragma unroll
    for (int rr = 0; rr < 8; ++rr) {
      int dd = g*8 + rr;
      Wk[dd][j] = Wkv[(size_t)(dc*32 + dd)*1024 + h*64 + j];
    }
#pragma unroll
    for (int rr = 0; rr < 16; ++rr) {
      int bb = g*16 + rr;
      qT[j][bb] = qbuf[(size_t)bb*512 + h*64 + j];
    }
  }
  __syncthreads();
  int b = t & 63, dq = t >> 6;
#pragma unroll
  for (int i = 0; i < 8; ++i) {
    int dd = dq*8 + i;
    float s = 0.f;
#pragma unroll 8
    for (int j = 0; j < 64; ++j) s += qT[j][b] * Wk[dd][j];
    u16[((size_t)b*16 + h)*1024 + dc*32 + dd] = (f16)s;
  }
}

// ---------------- lgk: logits[b][n][h] = sum_d x16[b][n][d] * u16[b][h][d] (MFMA, 1 wave) ----
// grid (16 m-tiles, 64 b). u16 rows 8..15 are zero-padded.
__global__ __launch_bounds__(64) void lgk(const f16* __restrict__ x16, const f16* __restrict__ u16,
                                          float* __restrict__ logitbuf) {
  int mt = blockIdx.x, b = blockIdx.y;
  int lane = threadIdx.x, l15 = lane & 15, l4 = lane >> 4;
  const f16* Ap = x16 + ((size_t)b*256 + mt*16 + l15)*1024 + 8*l4;
  const f16* Bp = u16 + ((size_t)b*16 + l15)*1024 + 8*l4;
  f32x4 acc = (f32x4){0.f,0.f,0.f,0.f};
#pragma unroll 8
  for (int ks = 0; ks < 32; ++ks)
    acc = __builtin_amdgcn_mfma_f32_16x16x32_f16(*(const half8*)(Ap + ks*32),
                                                 *(const half8*)(Bp + ks*32), acc, 0,0,0);
  if (l15 < 8) {
#pragma unroll
    for (int j = 0; j < 4; ++j)
      logitbuf[((size_t)b*256 + mt*16 + 4*l4 + j)*8 + l15] = acc[j];
  }
}

// ---------------- sm: softmax over n per (b,h); writes attnW f16 [b][16][256] (h>=8 zero) ----
__global__ __launch_bounds__(256) void sm(const float* __restrict__ logitbuf, f16* __restrict__ attnW) {
  int b = blockIdx.x, t = threadIdx.x;
  __shared__ float eL[256][9];
  __shared__ float Zs[8];
  float e[8];
  const float* lp = logitbuf + (size_t)b*256*8 + (size_t)t*8;
#pragma unroll
  for (int h = 0; h < 8; ++h) { e[h] = __expf(lp[h] * SCALE); eL[t][h] = e[h]; }
  __syncthreads();
  {
    int h = t >> 5, i = t & 31;
    float s = 0.f;
#pragma unroll
    for (int k = 0; k < 8; ++k) s += eL[i + 32*k][h];
#pragma unroll
    for (int o = 1; o < 32; o <<= 1) s += __shfl_xor(s, o);
    if (i == 0) Zs[h] = s;
  }
  __syncthreads();
#pragma unroll
  for (int h = 0; h < 8; ++h) attnW[((size_t)b*16 + h)*256 + t] = (f16)(e[h] / Zs[h]);
#pragma unroll
  for (int h = 8; h < 16; ++h) attnW[((size_t)b*16 + h)*256 + t] = (f16)0.f;
}

// ---------------- xbk: xbar[b][h][d] = sum_n attnW[b][h][n] * x[b][n][d] via xT (MFMA, 1 wave) ----
// grid (64 d-tiles, 64 b)
__global__ __launch_bounds__(64) void xbk(const f16* __restrict__ attnW, const f16* __restrict__ xT,
                                          f16* __restrict__ xbar) {
  int dt = blockIdx.x, b = blockIdx.y;
  int lane = threadIdx.x, l15 = lane & 15, l4 = lane >> 4;
  const f16* Ap = attnW + ((size_t)b*16 + l15)*256 + 8*l4;
  const f16* Bp = xT + ((size_t)b*1024 + dt*16 + l15)*256 + 8*l4;
  f32x4 acc = (f32x4){0.f,0.f,0.f,0.f};
#pragma unroll
  for (int ks = 0; ks < 8; ++ks)
    acc = __builtin_amdgcn_mfma_f32_16x16x32_f16(*(const half8*)(Ap + ks*32),
                                                 *(const half8*)(Bp + ks*32), acc, 0,0,0);
  if (l4 < 2) {
#pragma unroll
    for (int j = 0; j < 4; ++j)
      xbar[((size_t)b*8 + 4*l4 + j)*1024 + dt*16 + l15] = (f16)acc[j];
  }
}

// ---------------- vk: attnout[b][h*64+j] += sum_d xbar[b][h][d] * Wkv[d][512+h*64+j] ----
// grid (8 h, 4 dc, 4 bc); attnout pre-zeroed; atomicAdd partials over dc.
__global__ __launch_bounds__(256) void vk(const f16* __restrict__ xbar, const float* __restrict__ Wkv,
                                          float* __restrict__ attnout) {
  int h = blockIdx.x, dc = blockIdx.y, bc = blockIdx.z;
  int t = threadIdx.x;
  __shared__ float Wv[256][64];
  {
    int j = t & 63, g = t >> 6;
#pragma unroll
    for (int rr = 0; rr < 64; ++rr) {
      int dd = g*64 + rr;
      Wv[dd][j] = Wkv[(size_t)(dc*256 + dd)*1024 + 512 + h*64 + j];
    }
  }
  __syncthreads();
  int j = t & 63, bq = t >> 6;
  float s[4] = {0.f,0.f,0.f,0.f};
  const f16* xp[4];
#pragma unroll
  for (int bl = 0; bl < 4; ++bl)
    xp[bl] = xbar + ((size_t)(bc*16 + bq*4 + bl)*8 + h)*1024 + dc*256;
  for (int d8 = 0; d8 < 32; ++d8) {
    half8 xv[4];
#pragma unroll
    for (int bl = 0; bl < 4; ++bl) xv[bl] = *(const half8*)(xp[bl] + d8*8);
#pragma unroll
    for (int i = 0; i < 8; ++i) {
      float w = Wv[d8*8 + i][j];
#pragma unroll
      for (int bl = 0; bl < 4; ++bl) s[bl] += (float)xv[bl][i] * w;
    }
  }
#pragma unroll
  for (int bl = 0; bl < 4; ++bl)
    atomicAdd(&attnout[(size_t)(bc*16 + bq*4 + bl)*512 + h*64 + j], s[bl]);
}

// ---------------- spatial partial ----------------
__global__ __launch_bounds__(256) void spatialp(const float* __restrict__ attnout, const float* __restrict__ Wout,
                                                float* __restrict__ partial) {
  int ic = blockIdx.x, b = blockIdx.y;
  int t = threadIdx.x;
  __shared__ float ao[128];
  if (t < 128) ao[t] = attnout[(size_t)b*512 + ic*128 + t];
  __syncthreads();
  const float* W = Wout + (size_t)ic*128*1024 + t*4;
  f32x4 acc0 = (f32x4){0.f,0.f,0.f,0.f};
  f32x4 acc1 = (f32x4){0.f,0.f,0.f,0.f};
#pragma unroll 4
  for (int i = 0; i < 128; i += 2) {
    f32x4 w0 = *(const f32x4*)(W + (size_t)i*1024);
    f32x4 w1 = *(const f32x4*)(W + (size_t)(i+1)*1024);
    float a0 = ao[i], a1 = ao[i+1];
    acc0[0] += a0*w0[0]; acc0[1] += a0*w0[1]; acc0[2] += a0*w0[2]; acc0[3] += a0*w0[3];
    acc1[0] += a1*w1[0]; acc1[1] += a1*w1[1]; acc1[2] += a1*w1[2]; acc1[3] += a1*w1[3];
  }
  f32x4 acc;
#pragma unroll
  for (int j=0;j<4;++j) acc[j] = acc0[j] + acc1[j];
  *(f32x4*)(partial + ((size_t)(b*4 + ic))*1024 + t*4) = acc;
}

// ---------------- spatial reduce ----------------
__global__ __launch_bounds__(256) void spatialr(const float* __restrict__ partial, const float* __restrict__ bout,
                                                float* __restrict__ spatial) {
  int b = blockIdx.x, t = threadIdx.x;
  f32x4 s = *(const f32x4*)(bout + t*4);
#pragma unroll
  for (int ic = 0; ic < 4; ++ic) {
    f32x4 p = *(const f32x4*)(partial + ((size_t)(b*4 + ic))*1024 + t*4);
#pragma unroll
    for (int j=0;j<4;++j) s[j] += p[j];
  }
  *(f32x4*)(spatial + (size_t)b*1024 + t*4) = s;
}

// ---------------- spec v7: 64i x 1024e, 16 waves, 16 half-phases, 4-slot B ring + 3-slot A ring ----
// Loads issued 3 phases ahead; counted vmcnt never drains in the loop. No-max softmax,
// SCALE pre-folded into q_s. XCD-pinned batches.
__global__ __launch_bounds__(1024, 4) void speck(const f16* __restrict__ qks, const float* __restrict__ spatial,
                                                 float* __restrict__ r) {
  __shared__ f16 Bs[4][512*32];                       // 4 x 32 KB ring (e-half per phase)
  __shared__ f16 As[3][64*32];                        // 3 x 4 KB ring (per k-step)
  __shared__ __attribute__((aligned(16))) float sz[64*16];
  __shared__ float spat[64];
  __shared__ float zfin[64];
  int bid = blockIdx.x;
  int xcd = bid & 7, q = bid >> 3;
  int b = xcd*8 + (q >> 4);
  int iblk = q & 15;
  int t = threadIdx.x, lane = t & 63, wave = t >> 6;
  int l15 = lane & 15, l4 = lane >> 4;
  const f16* qs = qks + (size_t)b*1024*512;
  int i0 = iblk*64;
  if (t < 64) spat[t] = spatial[(size_t)b*1024 + i0 + t];

  f32x4 acc[4][4];
#pragma unroll
  for (int mi=0;mi<4;++mi)
#pragma unroll
    for (int ni=0;ni<4;++ni) acc[mi][ni] = (f32x4){0.f,0.f,0.f,0.f};
  int pc = (l4 ^ ((l15 >> 1) & 3)) * 8;

  // phase p: k-step ks = p>>1, e-half h = p&1. B slot p&3; A staged on even p into slot (p>>1)%3.
  // per-wave GLL counts: even p: w<4 -> 3, else 2; odd p: 2.
  auto STAGE = [&](int p) {
    int s = p & 3, hh = p & 1, ks = p >> 1;
    int k0 = ks*32;
#pragma unroll
    for (int c = 0; c < 2; ++c) {
      int u = c*1024 + t;
      int row = u >> 2;
      int ch = (u & 3) ^ ((u >> 3) & 3);
      GLL(qs + (size_t)(hh*512 + row)*512 + 256 + k0 + ch*8, &Bs[s][(c*1024 + wave*64)*8]);
    }
    if (hh == 0 && wave < 4) {
      int u = wave*64 + lane;
      int row = u >> 2;
      int ch = (u & 3) ^ ((u >> 3) & 3);
      GLL(qs + (size_t)(i0 + row)*512 + k0 + ch*8, &As[ks % 3][(wave*64)*8]);
    }
  };

  STAGE(0); STAGE(1); STAGE(2);
#pragma unroll
  for (int p = 0; p < 16; ++p) {
    // wait until phase p landed: remaining outstanding = count(p+1)+count(p+2)
    if (p < 14) {
      if (wave < 4) asm volatile("s_waitcnt vmcnt(5)" ::: "memory");
      else          asm volatile("s_waitcnt vmcnt(4)" ::: "memory");
    } else if (p == 14) {
      asm volatile("s_waitcnt vmcnt(2)" ::: "memory");
    } else {
      asm volatile("s_waitcnt vmcnt(0)" ::: "memory");
    }
    __builtin_amdgcn_s_barrier();
    __builtin_amdgcn_sched_barrier(0);
    if (p < 13) STAGE(p + 3);
    {
      int s = p & 3, hh = p & 1, sA = (p >> 1) % 3;
      half8 a[4];
#pragma unroll
      for (int mi = 0; mi < 4; ++mi)
        a[mi] = *(const half8*)(&As[sA][(mi*16 + l15)*32 + pc]);
      __builtin_amdgcn_s_setprio(1);
#pragma unroll
      for (int c = 0; c < 2; ++c) {
        half8 bb = *(const half8*)(&Bs[s][(wave*32 + c*16 + l15)*32 + pc]);
#pragma unroll
        for (int mi = 0; mi < 4; ++mi)
          acc[mi][hh*2+c] = __builtin_amdgcn_mfma_f32_16x16x32_f16(a[mi], bb, acc[mi][hh*2+c], 0,0,0);
      }
      __builtin_amdgcn_s_setprio(0);
      __builtin_amdgcn_sched_barrier(0);
    }
  }
  // ---- no-max softmax (f32-safe); acc[mi][ni] covers e = (ni>>1)*512 + wave*32 + (ni&1)*16 + l15 ----
#pragma unroll
  for (int mi=0;mi<4;++mi)
#pragma unroll
    for (int jj=0;jj<4;++jj) {
      float s = 0.f;
#pragma unroll
      for (int ni=0;ni<4;++ni) {
        float e = __expf(acc[mi][ni][jj]);
        acc[mi][ni][jj] = e;
        s += e;
      }
#pragma unroll
      for (int o=1;o<16;o<<=1) s += __shfl_xor(s, o);
      if (l15 == 0) sz[(mi*16 + 4*l4 + jj)*16 + wave] = s;
    }
  __syncthreads();
  {
    float v = sz[t];
#pragma unroll
    for (int o=1;o<16;o<<=1) v += __shfl_xor(v, o);
    if ((t & 15) == 0) zfin[t >> 4] = v;
  }
  __syncthreads();
  float f[4][4];
#pragma unroll
  for (int mi=0;mi<4;++mi)
#pragma unroll
    for (int jj=0;jj<4;++jj) {
      int row = mi*16 + 4*l4 + jj;
      f[mi][jj] = spat[row] / zfin[row];
    }
  float* rb = r + (size_t)b*1024;
#pragma unroll
  for (int ni=0;ni<4;++ni) {
    float v = 0.f;
#pragma unroll
    for (int mi=0;mi<4;++mi)
#pragma unroll
      for (int jj=0;jj<4;++jj) v += f[mi][jj]*acc[mi][ni][jj];
    v += __shfl_xor(v, 16);
    v += __shfl_xor(v, 32);
    if (l4 == 0) atomicAdd(rb + (ni>>1)*512 + wave*32 + (ni&1)*16 + l15, v);
  }
}

// ---------------- broadcast: out[b,n,:] = r[b,:] ----------------
__global__ __launch_bounds__(256) void bcast(const float* __restrict__ r, float* __restrict__ out) {
  size_t row = blockIdx.x;
  int b = (int)(row >> 8);
  f32x4 v = *(const f32x4*)(r + (size_t)b*1024 + threadIdx.x*4);
  *(f32x4*)(out + row*1024 + (size_t)threadIdx.x*4) = v;
}

extern "C" void kernel_launch(void* const* d_in, const int* in_sizes, int n_in,
                              void* d_out, int out_size, void* d_ws, size_t ws_size,
                              hipStream_t stream) {
  const float* x     = (const float*)d_in[0];
  const float* Wq    = (const float*)d_in[1];
  const float* Wkv   = (const float*)d_in[2];
  const float* Wout  = (const float*)d_in[3];
  const float* bout  = (const float*)d_in[4];
  const float* Wspec = (const float*)d_in[5];
  float* out = (float*)d_out;
  char* ws = (char*)d_ws;
  // workspace aliases (stream-ordered, all within the ~104 MB footprint used since round 1):
  //   ws+0..2M:   u16pad (memset->uk->lgk), then partial (spatialp->spatialr), then qks[0:2M]
  //   ws+2M:      logitbuf 512K (lgk->sm)
  //   ws+2.5M:    attnW 512K (sm->xbk)
  //   ws+3M:      xbar 1M (xbk->vk)
  //   ws+5M:      qbuf 128K (qk->uk)
  //   ws+0..64M:  qks (gemm_qs -> speck), overwrites all of the above (all dead by then)
  //   ws+32M:     x16 (prep_xf -> lgk), alias of qks upper half, dead before gemm_qs
  //   ws+64M:     xT 32M (prep_xf -> xbk, gemm_qs)
  f16*   qks      = (f16*)(ws);
  f16*   u16pad   = (f16*)(ws);
  float* partial  = (float*)(ws);
  float* logitbuf = (float*)(ws + 2097152);
  f16*   attnW    = (f16*)(ws + 2621440);
  f16*   xbar     = (f16*)(ws + 3145728);
  float* qbuf     = (float*)(ws + 5242880);
  f16*   x16      = (f16*)(ws + 33554432);
  f16*   xT       = (f16*)(ws + 67108864);
  f16*   WspecT   = (f16*)(ws + 102760448);
  float* attnout  = (float*)(ws + 103022592);
  float* spatial  = (float*)(ws + 103153664);
  float* rvec     = (float*)(ws + 103415808);
  (void)in_sizes; (void)n_in; (void)out_size; (void)ws_size;

  prep_xf    <<<dim3(32, 8, 64), dim3(256), 0, stream>>>(x, x16, xT);
  prep_WspecT<<<dim3(16, 8),     dim3(256), 0, stream>>>(Wspec, WspecT);
  hipMemsetAsync(u16pad, 0, 2097152, stream);
  hipMemsetAsync(attnout, 0, 64*512*sizeof(float), stream);
  qk         <<<dim3(64, 8),     dim3(256), 0, stream>>>(x, Wq, qbuf);
  uk         <<<dim3(8, 32),     dim3(256), 0, stream>>>(Wkv, qbuf, u16pad);
  lgk        <<<dim3(16, 64),    dim3(64),  0, stream>>>(x16, u16pad, logitbuf);
  sm         <<<dim3(64),        dim3(256), 0, stream>>>(logitbuf, attnW);
  xbk        <<<dim3(64, 64),    dim3(64),  0, stream>>>(attnW, xT, xbar);
  vk         <<<dim3(8, 4, 4),   dim3(256), 0, stream>>>(xbar, Wkv, attnout);
  spatialp   <<<dim3(4, 64),     dim3(256), 0, stream>>>(attnout, Wout, partial);
  spatialr   <<<dim3(64),        dim3(256), 0, stream>>>(partial, bout, spatial);
  gemm128<8,256,256,512,true><<<dim3(8, 4, 64), dim3(256), 0, stream>>>(xT, WspecT, qks,
                                                                   (size_t)1024*256, 0, (size_t)1024*512);
  hipMemsetAsync(rvec, 0, 64*1024*sizeof(float), stream);
  speck      <<<dim3(1024),      dim3(1024), 0, stream>>>(qks, spatial, rvec);
  bcast      <<<dim3(16384),     dim3(256), 0, stream>>>(rvec, out);
}